// Round 8
// baseline (58.100 us; speedup 1.0000x reference)
//
#include <hip/hip_runtime.h>

#define NEG_SLOPE 0.2f

typedef __bf16 bf16x8 __attribute__((ext_vector_type(8)));
typedef float  f32x4  __attribute__((ext_vector_type(4)));

__device__ __forceinline__ float leaky(float v)  { return fmaxf(v, NEG_SLOPE * v); }
__device__ __forceinline__ float relu_f(float v) { return v > 0.f ? v : 0.f; }

// ---------------- prep: W1/W2 -> bf16 MFMA B-fragment order in d_ws ----------------
// W1F[(n*64+l)*8+j]  = bf16(W1[(l4*8+j)*128 + n*16+l15])          (as R6/R7, validated)
// W2F[((ks*2+nn)*64+l)*8+j] = bf16(W2[(j*16+ks*4+l4)*32 + nn*16+l15])
//   row permutation compensates the z-store layout z_store[row][l15*8+n] (so the
//   layer-1 C->LDS write is 4x ds_write_b128 instead of 32x ds_write_b16).
__global__ __launch_bounds__(256)
void prep_weights(const float* __restrict__ W1, const float* __restrict__ W2,
                  __bf16* __restrict__ W1F, __bf16* __restrict__ W2F)
{
    int idx = blockIdx.x * 256 + threadIdx.x;   // 0..8191
    int half = idx >> 12;                        // 0: W1, 1: W2
    int e    = idx & 4095;
    int j   = e & 7;
    int l   = (e >> 3) & 63;
    int t   = e >> 9;                            // 0..7
    int l15 = l & 15;
    int l4  = l >> 4;
    if (half == 0) {
        W1F[e] = (__bf16)W1[(l4 * 8 + j) * 128 + t * 16 + l15];
    } else {
        int ks = t >> 1, nn = t & 1;
        W2F[e] = (__bf16)W2[(j * 16 + ks * 4 + l4) * 32 + nn * 16 + l15];
    }
}

// ================= K1: GAT only =================
// Block = 256 threads = 4 waves, 64 samples/block.
// wave w -> g = w&1 (graph), ch = (w>>1)&1 (channel half, 8 ch); lane = sample.
// LDS = 9216 B (logit-partial exchange only); ONE barrier; h stored to hbase.
__global__ __launch_bounds__(256)
void gat_kernel(
    const float* __restrict__ agent_pos, const float* __restrict__ agent_vel,
    const float* __restrict__ rel_lm, const float* __restrict__ other_pos,
    const float* __restrict__ lm_pos,
    const float* __restrict__ Wl, const float* __restrict__ bl,
    const float* __restrict__ Wr, const float* __restrict__ br,
    const float* __restrict__ We, const float* __restrict__ att,
    const float* __restrict__ bias,
    char* __restrict__ hbase, long hstride, int Btot)
{
    __shared__ float lds_lp[2][2][64][9];   // [g][ch][sample][edge]

    const int tid  = threadIdx.x;
    const int lane = tid & 63;
    const int w    = tid >> 6;
    const int g    = __builtin_amdgcn_readfirstlane(w & 1);
    const int ch   = __builtin_amdgcn_readfirstlane((w >> 1) & 1);
    const int CB   = ch * 8;

    int b = blockIdx.x * 64 + lane;
    if (b >= Btot) b = Btot - 1;            // clamp reads; barrier stays uniform

    const int o0[3] = {1, 0, 0};
    const int o1[3] = {2, 2, 1};

    // ---- positions (uniform branch) ----
    float px[3], py[3];
    if (g == 0) {
        const float2* ap = reinterpret_cast<const float2*>(agent_pos + b * 6);
#pragma unroll
        for (int j = 0; j < 3; ++j) { px[j] = ap[j].x; py[j] = ap[j].y; }
    } else {
        const float2* lp2 = reinterpret_cast<const float2*>(lm_pos + b * 18);
#pragma unroll
        for (int m = 0; m < 3; ++m) { px[m] = lp2[m].x; py[m] = lp2[m].y; }
    }

    // ---- pairwise distances (sqrtf(0)==0, guard unnecessary) ----
    float d01, d02, d12;
    {
        float dx, dy;
        dx = px[0] - px[1]; dy = py[0] - py[1]; d01 = sqrtf(dx * dx + dy * dy);
        dx = px[0] - px[2]; dy = py[0] - py[2]; d02 = sqrtf(dx * dx + dy * dy);
        dx = px[1] - px[2]; dy = py[1] - py[2]; d12 = sqrtf(dx * dx + dy * dy);
    }

    // ---- xl/xr for my 8 channels (weights scalar: CB uniform) ----
    float xl[3][8], xr[3][8];
#pragma unroll
    for (int j = 0; j < 3; ++j) {
        float xf[14];
        if (g == 0) {
            const float2 vel = reinterpret_cast<const float2*>(agent_vel + b * 6)[j];
            const float2* rl = reinterpret_cast<const float2*>(rel_lm + b * 18 + j * 6);
            const float4 op  = reinterpret_cast<const float4*>(other_pos + b * 12)[j];
            xf[0] = px[j]; xf[1] = py[j];
            xf[2] = vel.x; xf[3] = vel.y;
            xf[4] = rl[0].x; xf[5] = rl[0].y;
            xf[6] = rl[1].x; xf[7] = rl[1].y;
            xf[8] = rl[2].x; xf[9] = rl[2].y;
            xf[10] = op.x; xf[11] = op.y; xf[12] = op.z; xf[13] = op.w;
        } else {
            xf[0] = px[j]; xf[1] = py[j];
            xf[2] = 0.f;   xf[3] = 0.f;
#pragma unroll
            for (int m = 0; m < 3; ++m) {
                xf[4 + 2 * m] = px[m] - px[j];
                xf[5 + 2 * m] = py[m] - py[j];
            }
            const int a = o0[j], c2 = o1[j];
            xf[10] = px[a]  - px[j]; xf[11] = py[a]  - py[j];
            xf[12] = px[c2] - px[j]; xf[13] = py[c2] - py[j];
        }
#pragma unroll
        for (int cc = 0; cc < 8; ++cc) { xl[j][cc] = bl[CB + cc]; xr[j][cc] = br[CB + cc]; }
#pragma unroll
        for (int k = 0; k < 14; ++k) {
#pragma unroll
            for (int cc = 0; cc < 8; ++cc) {
                xl[j][cc] = fmaf(xf[k], Wl[k * 16 + CB + cc], xl[j][cc]);
                xr[j][cc] = fmaf(xf[k], Wr[k * 16 + CB + cc], xr[j][cc]);
            }
        }
    }

    // ---- logit partials over my 8 channels, all 9 edges ----
    float lp[9];
#pragma unroll
    for (int i = 0; i < 3; ++i) {
#pragma unroll
        for (int j = 0; j < 3; ++j) {
            float axv, ayv, adv;
            if (i == j) {
                const int a = o0[i], c2 = o1[i];
                axv = 0.5f * (px[a] + px[c2]) - px[i];
                ayv = 0.5f * (py[a] + py[c2]) - py[i];
                const float dA = (i == 0) ? d01 : ((i == 1) ? d01 : d02);
                const float dB = (i == 0) ? d02 : ((i == 1) ? d12 : d12);
                adv = 0.5f * (dA + dB);
            } else {
                axv = px[j] - px[i];
                ayv = py[j] - py[i];
                adv = ((i == 0 && j == 1) || (i == 1 && j == 0)) ? d01
                    : ((i == 0 && j == 2) || (i == 2 && j == 0)) ? d02 : d12;
            }
            float acc = 0.f;
#pragma unroll
            for (int cc = 0; cc < 8; ++cc) {
                float gg = xl[j][cc] + xr[i][cc];
                gg = fmaf(axv, We[CB + cc], gg);
                gg = fmaf(ayv, We[16 + CB + cc], gg);
                gg = fmaf(adv, We[32 + CB + cc], gg);
                acc = fmaf(leaky(gg), att[CB + cc], acc);
            }
            lp[j * 3 + i] = acc;
        }
    }

    // ---- exchange partials with sibling channel-half ----
#pragma unroll
    for (int e = 0; e < 9; ++e) lds_lp[g][ch][lane][e] = lp[e];
    __syncthreads();    // B1 (the only barrier)

    float lg[9];
#pragma unroll
    for (int e = 0; e < 9; ++e) lg[e] = lp[e] + lds_lp[g][1 - ch][lane][e];

    // ---- softmax per target (no max-sub: |logit| << 80) + pooled relu-sum ----
    float hs[8] = {0.f, 0.f, 0.f, 0.f, 0.f, 0.f, 0.f, 0.f};
#pragma unroll
    for (int i = 0; i < 3; ++i) {
        float e0 = __expf(lg[i]);
        float e1 = __expf(lg[3 + i]);
        float e2 = __expf(lg[6 + i]);
        float inv = __builtin_amdgcn_rcpf(e0 + e1 + e2);
        float a0 = e0 * inv, a1 = e1 * inv, a2 = e2 * inv;
#pragma unroll
        for (int cc = 0; cc < 8; ++cc) {
            float v = fmaf(a0, xl[0][cc],
                      fmaf(a1, xl[1][cc],
                      fmaf(a2, xl[2][cc], bias[CB + cc])));
            hs[cc] += relu_f(v);
        }
    }

    // ---- store pooled h (bf16x8, 16B) straight to the h buffer ----
    bf16x8 hv;
#pragma unroll
    for (int cc = 0; cc < 8; ++cc) hv[cc] = (__bf16)hs[cc];
    *reinterpret_cast<bf16x8*>(hbase + (size_t)b * hstride + (g * 16 + CB) * 2) = hv;
}

// ================= K2: MLP via MFMA 16x16x32 bf16 =================
// 4 waves/block, each wave handles TPW tiles of 16 samples. W-frags in VGPRs.
// z relayout: z_store[row][l15*8+n] -> 4x ds_write_b128; W2F rows permuted to match.
#define TPW 2
__global__ __launch_bounds__(256)
void mlp_kernel(const char* __restrict__ hbase, long hstride,
                const bf16x8* __restrict__ W1F, const bf16x8* __restrict__ W2F,
                const float* __restrict__ b1, const float* __restrict__ b2,
                float* __restrict__ out, int nTiles)
{
    __shared__ alignas(16) __bf16 lds_z[4][16][136];   // per-wave, stride 272B

    const int tid  = threadIdx.x;
    const int lane = tid & 63;
    const int wu   = __builtin_amdgcn_readfirstlane(tid >> 6);
    const int l15  = lane & 15;
    const int l4   = lane >> 4;
    const f32x4 zero4 = {0.f, 0.f, 0.f, 0.f};

    // hoist fragments + biases (L2-hot, once per wave)
    bf16x8 w1f[8], w2f[8];
#pragma unroll
    for (int n = 0; n < 8; ++n) w1f[n] = W1F[(n << 6) | lane];
#pragma unroll
    for (int t = 0; t < 8; ++t) w2f[t] = W2F[(t << 6) | lane];
    float b1v[8], b2v[2];
#pragma unroll
    for (int n = 0; n < 8; ++n) b1v[n] = b1[n * 16 + l15];
#pragma unroll
    for (int nn = 0; nn < 2; ++nn) b2v[nn] = b2[nn * 16 + l15];

    const int tile0 = (blockIdx.x * 4 + wu) * TPW;
#pragma unroll
    for (int tt = 0; tt < TPW; ++tt) {
        const int tile = tile0 + tt;
        if (tile >= nTiles) break;
        const int row0 = tile * 16;

        // layer 1: A-frag = h[row0+l15][l4*8..+8]
        bf16x8 a1 = *reinterpret_cast<const bf16x8*>(
            hbase + (size_t)(row0 + l15) * hstride + l4 * 16);
        f32x4 acc[8];
#pragma unroll
        for (int n = 0; n < 8; ++n)
            acc[n] = __builtin_amdgcn_mfma_f32_16x16x32_bf16(a1, w1f[n], zero4, 0, 0, 0);

        // bias + relu + cvt; z_store[row=l4*4+r][l15*8+n] -> one b128 per r
#pragma unroll
        for (int r = 0; r < 4; ++r) {
            bf16x8 zv;
#pragma unroll
            for (int n = 0; n < 8; ++n) zv[n] = (__bf16)relu_f(acc[n][r] + b1v[n]);
            *reinterpret_cast<bf16x8*>(&lds_z[wu][l4 * 4 + r][l15 * 8]) = zv;
        }

        // layer 2 (same-wave z reuse; compiler inserts lgkmcnt waits)
        f32x4 o2[2] = {zero4, zero4};
#pragma unroll
        for (int ks = 0; ks < 4; ++ks) {
            bf16x8 a2 = *reinterpret_cast<const bf16x8*>(&lds_z[wu][l15][ks * 32 + l4 * 8]);
#pragma unroll
            for (int nn = 0; nn < 2; ++nn)
                o2[nn] = __builtin_amdgcn_mfma_f32_16x16x32_bf16(a2, w2f[ks * 2 + nn], o2[nn], 0, 0, 0);
        }

        // store: lane holds o[l4*4+r][nn*16+l15]
#pragma unroll
        for (int nn = 0; nn < 2; ++nn) {
#pragma unroll
            for (int r = 0; r < 4; ++r) {
                int row = row0 + l4 * 4 + r;
                out[(size_t)row * 32 + nn * 16 + l15] = o2[nn][r] + b2v[nn];
            }
        }
    }
}

extern "C" void kernel_launch(void* const* d_in, const int* in_sizes, int n_in,
                              void* d_out, int out_size, void* d_ws, size_t ws_size,
                              hipStream_t stream) {
    const float* agent_pos = (const float*)d_in[0];
    const float* agent_vel = (const float*)d_in[1];
    const float* rel_lm    = (const float*)d_in[2];
    const float* other_pos = (const float*)d_in[3];
    const float* lm_pos    = (const float*)d_in[4];
    const float* Wl   = (const float*)d_in[5];
    const float* bl   = (const float*)d_in[6];
    const float* Wr   = (const float*)d_in[7];
    const float* br   = (const float*)d_in[8];
    const float* We   = (const float*)d_in[9];
    const float* att  = (const float*)d_in[10];
    const float* bias = (const float*)d_in[11];
    const float* W1   = (const float*)d_in[12];
    const float* b1   = (const float*)d_in[13];
    const float* W2   = (const float*)d_in[14];
    const float* b2   = (const float*)d_in[15];
    float* out = (float*)d_out;

    int B = in_sizes[0] / 6;                       // agent_pos is [B,3,2]

    __bf16* W1F = (__bf16*)d_ws;                   // 8 KB
    __bf16* W2F = (__bf16*)((char*)d_ws + 8192);   // 8 KB

    // h buffer: d_ws if it fits, else overlay in the upper half of out rows
    size_t need = 16384 + (size_t)B * 64;
    char* hbase; long hstride;
    if (ws_size >= need) { hbase = (char*)d_ws + 16384; hstride = 64; }
    else                 { hbase = (char*)out + 64;     hstride = 128; }

    prep_weights<<<32, 256, 0, stream>>>(W1, W2, W1F, W2F);

    int grid1 = (B + 63) / 64;
    gat_kernel<<<grid1, 256, 0, stream>>>(
        agent_pos, agent_vel, rel_lm, other_pos, lm_pos,
        Wl, bl, Wr, br, We, att, bias, hbase, hstride, B);

    int nTiles = (B + 15) / 16;
    int grid2 = (nTiles + 4 * TPW - 1) / (4 * TPW);
    mlp_kernel<<<grid2, 256, 0, stream>>>(
        hbase, hstride, (const bf16x8*)W1F, (const bf16x8*)W2F, b1, b2, out, nTiles);
}

// Round 9
// 45.329 us; speedup vs baseline: 1.2818x; 1.2818x over previous
//
#include <hip/hip_runtime.h>

#define NEG_SLOPE 0.2f

typedef __bf16 bf16x8 __attribute__((ext_vector_type(8)));
typedef float  f32x4  __attribute__((ext_vector_type(4)));
typedef float  f32x2  __attribute__((ext_vector_type(2)));

__device__ __forceinline__ float relu_f(float v) { return v > 0.f ? v : 0.f; }
__device__ __forceinline__ f32x2 pk_fma(f32x2 a, f32x2 b, f32x2 c) { return __builtin_elementwise_fma(a, b, c); }
__device__ __forceinline__ f32x2 pk_max(f32x2 a, f32x2 b) { return __builtin_elementwise_max(a, b); }
__device__ __forceinline__ f32x2 splat2(float s) { f32x2 r = {s, s}; return r; }
__device__ __forceinline__ f32x2 ld2(const float* p) { return *reinterpret_cast<const f32x2*>(p); }

// ---------------- prep: W1/W2 -> bf16 MFMA B-fragment order in d_ws ----------------
// (validated R7/R8) W1F[(n*64+l)*8+j] = bf16(W1[(l4*8+j)*128 + n*16+l15])
// W2F[((ks*2+nn)*64+l)*8+j] = bf16(W2[(j*16+ks*4+l4)*32 + nn*16+l15])  (row-permuted
// to match the z_store[row][l15*8+n] layout -> layer-1 C write is 4x ds_write_b128).
__global__ __launch_bounds__(256)
void prep_weights(const float* __restrict__ W1, const float* __restrict__ W2,
                  __bf16* __restrict__ W1F, __bf16* __restrict__ W2F)
{
    int idx = blockIdx.x * 256 + threadIdx.x;   // 0..8191
    int half = idx >> 12;                        // 0: W1, 1: W2
    int e    = idx & 4095;
    int j   = e & 7;
    int l   = (e >> 3) & 63;
    int t   = e >> 9;                            // 0..7
    int l15 = l & 15;
    int l4  = l >> 4;
    if (half == 0) {
        W1F[e] = (__bf16)W1[(l4 * 8 + j) * 128 + t * 16 + l15];
    } else {
        int ks = t >> 1, nn = t & 1;
        W2F[e] = (__bf16)W2[(j * 16 + ks * 4 + l4) * 32 + nn * 16 + l15];
    }
}

// ================= K1: GAT only, packed-fp32 channel math =================
// Block = 256 threads = 4 waves, 64 samples/block.
// wave w -> g = w&1 (graph), ch = (w>>1)&1 (channel half, 8 ch = 4 f32x2);
// lane = sample. All channel loops are f32x2 -> V_PK_* (VOP3P, 2 ch/inst).
__global__ __launch_bounds__(256)
void gat_kernel(
    const float* __restrict__ agent_pos, const float* __restrict__ agent_vel,
    const float* __restrict__ rel_lm, const float* __restrict__ other_pos,
    const float* __restrict__ lm_pos,
    const float* __restrict__ Wl, const float* __restrict__ bl,
    const float* __restrict__ Wr, const float* __restrict__ br,
    const float* __restrict__ We, const float* __restrict__ att,
    const float* __restrict__ bias,
    char* __restrict__ hbase, long hstride, int Btot)
{
    __shared__ float lds_lp[2][2][64][9];   // [g][ch][sample][edge]

    const int tid  = threadIdx.x;
    const int lane = tid & 63;
    const int w    = tid >> 6;
    const int g    = __builtin_amdgcn_readfirstlane(w & 1);
    const int ch   = __builtin_amdgcn_readfirstlane((w >> 1) & 1);
    const int CB   = ch * 8;

    int b = blockIdx.x * 64 + lane;
    if (b >= Btot) b = Btot - 1;            // clamp reads; barrier stays uniform

    const int o0[3] = {1, 0, 0};
    const int o1[3] = {2, 2, 1};

    // ---- positions (uniform branch) ----
    float px[3], py[3];
    if (g == 0) {
        const float2* ap = reinterpret_cast<const float2*>(agent_pos + b * 6);
#pragma unroll
        for (int j = 0; j < 3; ++j) { px[j] = ap[j].x; py[j] = ap[j].y; }
    } else {
        const float2* lp2 = reinterpret_cast<const float2*>(lm_pos + b * 18);
#pragma unroll
        for (int m = 0; m < 3; ++m) { px[m] = lp2[m].x; py[m] = lp2[m].y; }
    }

    // ---- pairwise distances ----
    float d01, d02, d12;
    {
        float dx, dy;
        dx = px[0] - px[1]; dy = py[0] - py[1]; d01 = sqrtf(dx * dx + dy * dy);
        dx = px[0] - px[2]; dy = py[0] - py[2]; d02 = sqrtf(dx * dx + dy * dy);
        dx = px[1] - px[2]; dy = py[1] - py[2]; d12 = sqrtf(dx * dx + dy * dy);
    }

    // ---- xl/xr for my 8 channels as 4x f32x2 (weights -> SGPR pairs) ----
    f32x2 xl[3][4], xr[3][4];
#pragma unroll
    for (int j = 0; j < 3; ++j) {
        float xf[14];
        if (g == 0) {
            const float2 vel = reinterpret_cast<const float2*>(agent_vel + b * 6)[j];
            const float2* rl = reinterpret_cast<const float2*>(rel_lm + b * 18 + j * 6);
            const float4 op  = reinterpret_cast<const float4*>(other_pos + b * 12)[j];
            xf[0] = px[j]; xf[1] = py[j];
            xf[2] = vel.x; xf[3] = vel.y;
            xf[4] = rl[0].x; xf[5] = rl[0].y;
            xf[6] = rl[1].x; xf[7] = rl[1].y;
            xf[8] = rl[2].x; xf[9] = rl[2].y;
            xf[10] = op.x; xf[11] = op.y; xf[12] = op.z; xf[13] = op.w;
        } else {
            xf[0] = px[j]; xf[1] = py[j];
            xf[2] = 0.f;   xf[3] = 0.f;
#pragma unroll
            for (int m = 0; m < 3; ++m) {
                xf[4 + 2 * m] = px[m] - px[j];
                xf[5 + 2 * m] = py[m] - py[j];
            }
            const int a = o0[j], c2 = o1[j];
            xf[10] = px[a]  - px[j]; xf[11] = py[a]  - py[j];
            xf[12] = px[c2] - px[j]; xf[13] = py[c2] - py[j];
        }
#pragma unroll
        for (int cc = 0; cc < 4; ++cc) {
            xl[j][cc] = ld2(bl + CB + cc * 2);
            xr[j][cc] = ld2(br + CB + cc * 2);
        }
#pragma unroll
        for (int k = 0; k < 14; ++k) {
            f32x2 xk = splat2(xf[k]);
#pragma unroll
            for (int cc = 0; cc < 4; ++cc) {
                xl[j][cc] = pk_fma(xk, ld2(Wl + k * 16 + CB + cc * 2), xl[j][cc]);
                xr[j][cc] = pk_fma(xk, ld2(Wr + k * 16 + CB + cc * 2), xr[j][cc]);
            }
        }
    }

    // ---- logit partials over my 8 channels, all 9 edges (packed) ----
    float lp[9];
#pragma unroll
    for (int i = 0; i < 3; ++i) {
#pragma unroll
        for (int j = 0; j < 3; ++j) {
            float axv, ayv, adv;
            if (i == j) {
                const int a = o0[i], c2 = o1[i];
                axv = 0.5f * (px[a] + px[c2]) - px[i];
                ayv = 0.5f * (py[a] + py[c2]) - py[i];
                const float dA = (i == 0) ? d01 : ((i == 1) ? d01 : d02);
                const float dB = (i == 0) ? d02 : ((i == 1) ? d12 : d12);
                adv = 0.5f * (dA + dB);
            } else {
                axv = px[j] - px[i];
                ayv = py[j] - py[i];
                adv = ((i == 0 && j == 1) || (i == 1 && j == 0)) ? d01
                    : ((i == 0 && j == 2) || (i == 2 && j == 0)) ? d02 : d12;
            }
            f32x2 vax = splat2(axv), vay = splat2(ayv), vad = splat2(adv);
            f32x2 acc = {0.f, 0.f};
#pragma unroll
            for (int cc = 0; cc < 4; ++cc) {
                f32x2 gg = xl[j][cc] + xr[i][cc];
                gg = pk_fma(vax, ld2(We + CB + cc * 2), gg);
                gg = pk_fma(vay, ld2(We + 16 + CB + cc * 2), gg);
                gg = pk_fma(vad, ld2(We + 32 + CB + cc * 2), gg);
                f32x2 lk = pk_max(gg, gg * splat2(NEG_SLOPE));   // leaky relu
                acc = pk_fma(lk, ld2(att + CB + cc * 2), acc);
            }
            lp[j * 3 + i] = acc.x + acc.y;
        }
    }

    // ---- exchange partials with sibling channel-half ----
#pragma unroll
    for (int e = 0; e < 9; ++e) lds_lp[g][ch][lane][e] = lp[e];
    __syncthreads();    // B1 (the only barrier)

    float lg[9];
#pragma unroll
    for (int e = 0; e < 9; ++e) lg[e] = lp[e] + lds_lp[g][1 - ch][lane][e];

    // ---- softmax per target (no max-sub: logits are O(10)) + pooled relu-sum ----
    f32x2 hs[4] = {{0.f, 0.f}, {0.f, 0.f}, {0.f, 0.f}, {0.f, 0.f}};
    const f32x2 zero2 = {0.f, 0.f};
#pragma unroll
    for (int i = 0; i < 3; ++i) {
        float e0 = __expf(lg[i]);
        float e1 = __expf(lg[3 + i]);
        float e2 = __expf(lg[6 + i]);
        float inv = __builtin_amdgcn_rcpf(e0 + e1 + e2);
        f32x2 a0 = splat2(e0 * inv), a1 = splat2(e1 * inv), a2 = splat2(e2 * inv);
#pragma unroll
        for (int cc = 0; cc < 4; ++cc) {
            f32x2 v = pk_fma(a0, xl[0][cc],
                      pk_fma(a1, xl[1][cc],
                      pk_fma(a2, xl[2][cc], ld2(bias + CB + cc * 2))));
            hs[cc] += pk_max(v, zero2);
        }
    }

    // ---- store pooled h (bf16x8, 16B) ----
    bf16x8 hv;
#pragma unroll
    for (int cc = 0; cc < 4; ++cc) {
        hv[cc * 2 + 0] = (__bf16)hs[cc].x;
        hv[cc * 2 + 1] = (__bf16)hs[cc].y;
    }
    *reinterpret_cast<bf16x8*>(hbase + (size_t)b * hstride + (g * 16 + CB) * 2) = hv;
}

// ================= K2: MLP via MFMA 16x16x32 bf16 (validated R8) =================
#define TPW 2
__global__ __launch_bounds__(256)
void mlp_kernel(const char* __restrict__ hbase, long hstride,
                const bf16x8* __restrict__ W1F, const bf16x8* __restrict__ W2F,
                const float* __restrict__ b1, const float* __restrict__ b2,
                float* __restrict__ out, int nTiles)
{
    __shared__ alignas(16) __bf16 lds_z[4][16][136];   // per-wave, stride 272B

    const int tid  = threadIdx.x;
    const int lane = tid & 63;
    const int wu   = __builtin_amdgcn_readfirstlane(tid >> 6);
    const int l15  = lane & 15;
    const int l4   = lane >> 4;
    const f32x4 zero4 = {0.f, 0.f, 0.f, 0.f};

    bf16x8 w1f[8], w2f[8];
#pragma unroll
    for (int n = 0; n < 8; ++n) w1f[n] = W1F[(n << 6) | lane];
#pragma unroll
    for (int t = 0; t < 8; ++t) w2f[t] = W2F[(t << 6) | lane];
    float b1v[8], b2v[2];
#pragma unroll
    for (int n = 0; n < 8; ++n) b1v[n] = b1[n * 16 + l15];
#pragma unroll
    for (int nn = 0; nn < 2; ++nn) b2v[nn] = b2[nn * 16 + l15];

    const int tile0 = (blockIdx.x * 4 + wu) * TPW;
#pragma unroll
    for (int tt = 0; tt < TPW; ++tt) {
        const int tile = tile0 + tt;
        if (tile >= nTiles) break;
        const int row0 = tile * 16;

        bf16x8 a1 = *reinterpret_cast<const bf16x8*>(
            hbase + (size_t)(row0 + l15) * hstride + l4 * 16);
        f32x4 acc[8];
#pragma unroll
        for (int n = 0; n < 8; ++n)
            acc[n] = __builtin_amdgcn_mfma_f32_16x16x32_bf16(a1, w1f[n], zero4, 0, 0, 0);

#pragma unroll
        for (int r = 0; r < 4; ++r) {
            bf16x8 zv;
#pragma unroll
            for (int n = 0; n < 8; ++n) zv[n] = (__bf16)relu_f(acc[n][r] + b1v[n]);
            *reinterpret_cast<bf16x8*>(&lds_z[wu][l4 * 4 + r][l15 * 8]) = zv;
        }

        f32x4 o2[2] = {zero4, zero4};
#pragma unroll
        for (int ks = 0; ks < 4; ++ks) {
            bf16x8 a2 = *reinterpret_cast<const bf16x8*>(&lds_z[wu][l15][ks * 32 + l4 * 8]);
#pragma unroll
            for (int nn = 0; nn < 2; ++nn)
                o2[nn] = __builtin_amdgcn_mfma_f32_16x16x32_bf16(a2, w2f[ks * 2 + nn], o2[nn], 0, 0, 0);
        }

#pragma unroll
        for (int nn = 0; nn < 2; ++nn) {
#pragma unroll
            for (int r = 0; r < 4; ++r) {
                int row = row0 + l4 * 4 + r;
                out[(size_t)row * 32 + nn * 16 + l15] = o2[nn][r] + b2v[nn];
            }
        }
    }
}

extern "C" void kernel_launch(void* const* d_in, const int* in_sizes, int n_in,
                              void* d_out, int out_size, void* d_ws, size_t ws_size,
                              hipStream_t stream) {
    const float* agent_pos = (const float*)d_in[0];
    const float* agent_vel = (const float*)d_in[1];
    const float* rel_lm    = (const float*)d_in[2];
    const float* other_pos = (const float*)d_in[3];
    const float* lm_pos    = (const float*)d_in[4];
    const float* Wl   = (const float*)d_in[5];
    const float* bl   = (const float*)d_in[6];
    const float* Wr   = (const float*)d_in[7];
    const float* br   = (const float*)d_in[8];
    const float* We   = (const float*)d_in[9];
    const float* att  = (const float*)d_in[10];
    const float* bias = (const float*)d_in[11];
    const float* W1   = (const float*)d_in[12];
    const float* b1   = (const float*)d_in[13];
    const float* W2   = (const float*)d_in[14];
    const float* b2   = (const float*)d_in[15];
    float* out = (float*)d_out;

    int B = in_sizes[0] / 6;                       // agent_pos is [B,3,2]

    __bf16* W1F = (__bf16*)d_ws;                   // 8 KB
    __bf16* W2F = (__bf16*)((char*)d_ws + 8192);   // 8 KB

    size_t need = 16384 + (size_t)B * 64;
    char* hbase; long hstride;
    if (ws_size >= need) { hbase = (char*)d_ws + 16384; hstride = 64; }
    else                 { hbase = (char*)out + 64;     hstride = 128; }

    prep_weights<<<32, 256, 0, stream>>>(W1, W2, W1F, W2F);

    int grid1 = (B + 63) / 64;
    gat_kernel<<<grid1, 256, 0, stream>>>(
        agent_pos, agent_vel, rel_lm, other_pos, lm_pos,
        Wl, bl, Wr, br, We, att, bias, hbase, hstride, B);

    int nTiles = (B + 15) / 16;
    int grid2 = (nTiles + 4 * TPW - 1) / (4 * TPW);
    mlp_kernel<<<grid2, 256, 0, stream>>>(
        hbase, hstride, (const bf16x8*)W1F, (const bf16x8*)W2F, b1, b2, out, nTiles);
}